// Round 3
// baseline (88.302 us; speedup 1.0000x reference)
//
#include <hip/hip_runtime.h>

#define M_BASIS 100
constexpr float INV_TWO_PI = 0.15915494309189535f;

// One wave (64 lanes) per row, grid-strided. Lane l < 50 owns the j-pair
// {2l, 2l+1} and emits one float2 store -> the whole 400B row is a single
// global_store_dwordx2 instruction (50 active lanes).
// Basis params (mu + full 2x2 sigma) live in registers, loaded once.
__global__ __launch_bounds__(256) void cs_kernel(
    const float* __restrict__ theta,
    const float* __restrict__ basis_mu,
    const float* __restrict__ basis_sigma,
    float* __restrict__ out,
    int N)
{
    const int lane = threadIdx.x & 63;
    const int waves_per_block = blockDim.x >> 6;
    const int wave_id = blockIdx.x * waves_per_block + (threadIdx.x >> 6);
    const int num_waves = gridDim.x * waves_per_block;

    const bool active = (lane < (M_BASIS / 2));  // 50 lanes carry output

    // Registers: mu pair and both sigmas for j0=2l, j1=2l+1
    float4 mu2 = make_float4(0.f, 0.f, 0.f, 0.f);      // mu[j0].xy, mu[j1].xy
    float4 sA  = make_float4(1.f, 0.f, 0.f, 1.f);      // sigma[j0] row-major
    float4 sB  = make_float4(1.f, 0.f, 0.f, 1.f);      // sigma[j1]
    if (active) {
        mu2 = ((const float4*)basis_mu)[lane];          // 200 floats = 50 float4
        sA  = ((const float4*)basis_sigma)[2 * lane];
        sB  = ((const float4*)basis_sigma)[2 * lane + 1];
    }

    #pragma unroll 2
    for (int n = wave_id; n < N; n += num_waves) {
        const float* th = theta + n * 6;
        float2 e  = *(const float2*)(th);       // eta
        float2 qa = *(const float2*)(th + 2);   // q00 q01
        float2 qb = *(const float2*)(th + 4);   // q10 q11

        // P = -2Q; Sigma = sym(P^-1) = -0.5 * sym(Q^-1)
        float detQ = qa.x * qb.y - qa.y * qb.x;
        float r    = __builtin_amdgcn_rcpf(detQ);
        float h    = -0.5f * r;
        float S00  = qb.y * h;
        float S11  = qa.x * h;
        float S01  = (qa.y + qb.x) * (-0.5f * h);   // = 0.25*(q01+q10)*r
        float Mu0  = S00 * e.x + S01 * e.y;
        float Mu1  = S01 * e.x + S11 * e.y;

        if (active) {
            // ---- chunk j0 = 2*lane ----
            float c00 = S00 + sA.x, c01 = S01 + sA.y;
            float c10 = S01 + sA.z, c11 = S11 + sA.w;
            float d0 = Mu0 - mu2.x, d1 = Mu1 - mu2.y;
            float detC = c00 * c11 - c01 * c10;
            float rs   = __builtin_amdgcn_rsqf(detC);
            float invC = rs * rs;
            float t = d0 * d0, u = d1 * d1, dd = d0 * d1;
            float num = t * c11 + u * c00 - dd * (c01 + c10);
            float r0 = __expf(-0.5f * num * invC) * (INV_TWO_PI * rs);

            // ---- chunk j1 = 2*lane + 1 ----
            float e00 = S00 + sB.x, e01 = S01 + sB.y;
            float e10 = S01 + sB.z, e11 = S11 + sB.w;
            float f0 = Mu0 - mu2.z, f1 = Mu1 - mu2.w;
            float detE = e00 * e11 - e01 * e10;
            float rsE  = __builtin_amdgcn_rsqf(detE);
            float invE = rsE * rsE;
            float tE = f0 * f0, uE = f1 * f1, ddE = f0 * f1;
            float numE = tE * e11 + uE * e00 - ddE * (e01 + e10);
            float r1 = __expf(-0.5f * numE * invE) * (INV_TWO_PI * rsE);

            ((float2*)(out + (size_t)n * M_BASIS))[lane] = make_float2(r0, r1);
        }
    }
}

extern "C" void kernel_launch(void* const* d_in, const int* in_sizes, int n_in,
                              void* d_out, int out_size, void* d_ws, size_t ws_size,
                              hipStream_t stream) {
    const float* theta      = (const float*)d_in[0];   // [N,6]
    const float* basis_mu   = (const float*)d_in[1];   // [M,2]
    const float* basis_sig  = (const float*)d_in[2];   // [M,2,2]
    float* out = (float*)d_out;                        // [N,M]

    int N = in_sizes[0] / 6;
    int block = 256;   // 4 waves/block
    int grid = 4096;   // 16384 waves -> 8 rows per wave
    hipLaunchKernelGGL(cs_kernel, dim3(grid), dim3(block), 0, stream,
                       theta, basis_mu, basis_sig, out, N);
}